// Round 17
// baseline (267.032 us; speedup 1.0000x reference)
//
#include <hip/hip_runtime.h>

#define CIN 48
#define COUT 48
#define NPIX 16384  // 128*128
#define XFP 52      // XF pitch in shorts (104 B): bank conflicts 5.8M -> 0.88M (R11/R12)

typedef float f32x4 __attribute__((ext_vector_type(4)));
typedef short bf16x8 __attribute__((ext_vector_type(8)));

__device__ __forceinline__ unsigned short f2bf(float f) {
  unsigned u = __float_as_uint(f);
  unsigned r = (u + 0x7FFFu + ((u >> 16) & 1u)) >> 16;  // RNE
  return (unsigned short)r;
}
__device__ __forceinline__ float bf2f(unsigned short b) {
  return __uint_as_float(((unsigned)b) << 16);
}

// ws layout (floats):
//   w[20736] | ar[128] | ai[128] | pad->21248 | Up[1572864] | yf[786432] |
//   wbf64[13824] | wsplit[73728] | xfg[18874368]
#define OFF_UP     21248
#define OFF_YF     (OFF_UP + CIN * NPIX * 2)
#define OFF_WBF64  (OFF_YF + CIN * NPIX)
#define OFF_WSPLIT (OFF_WBF64 + 13824)
#define OFF_XFG    (OFF_WSPLIT + 73728)
#define WS_NEEDED  ((size_t)(OFF_XFG + 48 * 48 * NPIX / 2) * 4)

// ---------------------------------------------------------------------------
// K1: Gabor weights (unchanged, passing)
// ---------------------------------------------------------------------------
__global__ __launch_bounds__(256) void gabor_k(
    const float* __restrict__ freq, const float* __restrict__ theta,
    const float* __restrict__ sigma, const float* __restrict__ psi,
    const float* __restrict__ f0, const float* __restrict__ theta0,
    float* __restrict__ wout, unsigned short* __restrict__ wbf64,
    unsigned int* __restrict__ wsplitU, int big)
{
  int idx = blockIdx.x * 256 + threadIdx.x;
  if (idx < 432 * 16) {
    wbf64[(idx >> 4) * 64 + 48 + (idx & 15)] = 0;
  }
  if (big && idx < 2304 * 14) {
    int row = idx / 14, q = idx - row * 14;
    wsplitU[row * 32 + 18 + q] = 0u;
  }
  if (idx >= COUT * CIN * 9) return;
  int k = idx % 9;
  int oi = idx / 9;
  int oc = oi / CIN, ic = oi % CIN;
  int a = k / 3, b = k % 3;
  float Yv = (a == 0) ? -1.0f : ((a == 1) ? 0.5f : 2.0f);
  float Xv = (b == 0) ? -1.0f : ((b == 1) ? 0.5f : 2.0f);
  float th = theta[oi], sg = sigma[oi], fr = freq[oi], ps = psi[oi];
  float F0 = f0[oi], th0 = theta0[oi];
  float c = cosf(th), s = sinf(th);
  float rotx =  Xv * c + Yv * s;
  float roty = -Xv * s + Yv * c;
  float r = sqrtf(rotx * rotx + roty * roty + 0.001f);
  float denom = 2.0f * logf(sg / F0);
  float t1 = (logf(r) - logf(F0)) / denom;
  float g_rad = expf(-t1 * t1);
  float dth = th - th0;
  float g_ang = expf(-dth * dth / (2.0f * sg * sg));
  float g = g_rad * g_ang * cosf(fr * r + ps) / (6.283185307179586f * sg * sg);
  wout[idx] = g;
  wbf64[(k * 48 + oc) * 64 + ic] = f2bf(g);
  if (big) {
    unsigned short w0 = f2bf(g);
    unsigned short w1 = f2bf(g - bf2f(w0));
    unsigned int u0 = (unsigned)w0 | ((unsigned)w0 << 16);
    unsigned int u1 = (unsigned)w1 | ((unsigned)w1 << 16);
    unsigned int* rowp = wsplitU + (ic * 48 + oc) * 32;
    rowp[k * 2]     = u0;
    rowp[k * 2 + 1] = u1;
  }
}

// ---------------------------------------------------------------------------
// K2: circulant band-limit vector
// ---------------------------------------------------------------------------
__global__ void circ_k(float* __restrict__ ar, float* __restrict__ ai)
{
  int d = threadIdx.x;
  float sr = 0.f, si = 0.f;
  for (int u = 34; u < 94; ++u) {
    int m = (u * d) & 127;
    float ang = (float)m * 0.049087385212340526f;
    sr += cosf(ang);
    si += sinf(ang);
  }
  ar[d] = sr * (1.0f / 128.0f);
  ai[d] = si * (1.0f / 128.0f);
}

// ---------------------------------------------------------------------------
// K3a: row band-limit. grid (8, 48).
// ---------------------------------------------------------------------------
__global__ __launch_bounds__(256) void stage1_k(
    const float* __restrict__ x, const float* __restrict__ arr,
    const float* __restrict__ aii, float2* __restrict__ Up)
{
  __shared__ float Xs[16 * 128];
  __shared__ float ars[128], ais[128];
  int yg = blockIdx.x, i = blockIdx.y;
  int t = threadIdx.x;
  const float* Xi = x + i * NPIX + yg * 16 * 128;
  for (int p = t; p < 2048; p += 256) Xs[p] = Xi[p];
  if (t < 128) { ars[t] = arr[t]; ais[t] = aii[t]; }
  __syncthreads();
  int j = t & 127;
  int ysl = t >> 7;
  float accr[8], acci[8];
#pragma unroll
  for (int yy = 0; yy < 8; ++yy) { accr[yy] = 0.f; acci[yy] = 0.f; }
  for (int xx = 0; xx < 128; ++xx) {
    float tr = ars[(j - xx) & 127];
    float ti = ais[(j - xx) & 127];
#pragma unroll
    for (int yy = 0; yy < 8; ++yy) {
      float xv = Xs[(ysl * 8 + yy) * 128 + xx];
      accr[yy] += xv * tr;
      acci[yy] += xv * ti;
    }
  }
  float2* UpI = Up + i * NPIX;
  int ybase = yg * 16 + ysl * 8;
#pragma unroll
  for (int yy = 0; yy < 8; ++yy)
    UpI[(ybase + yy) * 128 + j] = make_float2(accr[yy], acci[yy]);
}

// ---------------------------------------------------------------------------
// K3b: column band-limit. grid (8, 48). f32 output (R7: bf16 yf fails).
// ---------------------------------------------------------------------------
__global__ __launch_bounds__(256) void stage2_k(
    const float2* __restrict__ Up, const float* __restrict__ arr,
    const float* __restrict__ aii, float* __restrict__ yf)
{
  __shared__ float2 Us[128 * 16];
  __shared__ float ars[128], ais[128];
  int jg = blockIdx.x, i = blockIdx.y;
  int t = threadIdx.x;
  const float2* UpI = Up + i * NPIX;
  for (int p = t; p < 2048; p += 256) {
    int y = p >> 4, jj = p & 15;
    Us[p] = UpI[y * 128 + jg * 16 + jj];
  }
  if (t < 128) { ars[t] = arr[t]; ais[t] = aii[t]; }
  __syncthreads();
  int yp = t & 127;
  int xsl = t >> 7;
  float acc[8];
#pragma unroll
  for (int xx = 0; xx < 8; ++xx) acc[xx] = 0.f;
  for (int y = 0; y < 128; ++y) {
    float tr = ars[(yp - y) & 127];
    float ti = ais[(yp - y) & 127];
#pragma unroll
    for (int xx = 0; xx < 8; ++xx) {
      float2 u = Us[y * 16 + xsl * 8 + xx];
      acc[xx] += u.x * tr - u.y * ti;
    }
  }
  float* yfI = yf + i * NPIX;
  int xb = jg * 16 + xsl * 8;
#pragma unroll
  for (int xx = 0; xx < 8; ++xx)
    yfI[yp * 128 + xb + xx] = acc[xx];
}

// ---------------------------------------------------------------------------
// K4a: inner 3x3 circular conv as MFMA GEMM per i (unchanged, passing)
// ---------------------------------------------------------------------------
__global__ __launch_bounds__(256, 3) void stageA_k(
    const float* __restrict__ yf, const unsigned short* __restrict__ wsplit,
    unsigned short* __restrict__ xfg)
{
  __shared__ unsigned int bpU[512];
  __shared__ __align__(16) unsigned int BU[256 * 34];
  int Y0 = blockIdx.x * 2, i = blockIdx.y;
  int tid = threadIdx.x;
  const float* yfi = yf + i * NPIX;

  for (int j = tid; j < 512; j += 256) {
    int r = j >> 7, cx = j & 127;
    int gy = (Y0 - 2 + r) & 127;
    float v = yfi[gy * 128 + cx];
    unsigned short b0 = f2bf(v);
    unsigned short b1 = f2bf(v - bf2f(b0));
    bpU[j] = (unsigned)b0 | ((unsigned)b1 << 16);
  }
  __syncthreads();

  {
    int px = tid;
    int ry = px >> 7, xx = px & 127;
    unsigned int* brow = BU + px * 34;
#pragma unroll
    for (int k = 0; k < 9; ++k) {
      int dy = k / 3, dx = k - dy * 3;
      int r = 2 + ry - dy;
      int c = (xx - dx) & 127;
      unsigned int pr = bpU[r * 128 + c];
      brow[2 * k] = pr;
      brow[2 * k + 1] = pr;
    }
#pragma unroll
    for (int q = 18; q < 34; ++q) brow[q] = 0u;
  }
  __syncthreads();

  int wv = tid >> 6, lane = tid & 63;
  int tx = lane & 15, gq = lane >> 4;
  f32x4 acc[4][3];
#pragma unroll
  for (int nn = 0; nn < 4; ++nn)
#pragma unroll
    for (int m = 0; m < 3; ++m) acc[nn][m] = (f32x4){0.f, 0.f, 0.f, 0.f};

  const unsigned short* wsA = wsplit + i * (48 * 64);
#pragma unroll
  for (int half = 0; half < 2; ++half) {
    bf16x8 Af[3];
#pragma unroll
    for (int m = 0; m < 3; ++m)
      Af[m] = *(const bf16x8*)(wsA + (m * 16 + tx) * 64 + half * 32 + gq * 8);
#pragma unroll
    for (int nn = 0; nn < 4; ++nn) {
      int px = (wv * 4 + nn) * 16 + tx;
      bf16x8 Bf = *(const bf16x8*)((const short*)BU + px * 68 + half * 32 + gq * 8);
#pragma unroll
      for (int m = 0; m < 3; ++m)
        acc[nn][m] = __builtin_amdgcn_mfma_f32_16x16x32_bf16(Af[m], Bf, acc[nn][m], 0, 0, 0);
    }
  }

#pragma unroll
  for (int nn = 0; nn < 4; ++nn) {
    int p = Y0 * 128 + (wv * 4 + nn) * 16 + tx;
#pragma unroll
    for (int m = 0; m < 3; ++m) {
#pragma unroll
      for (int r = 0; r < 4; ++r) {
        int o = m * 16 + gq * 4 + r;
        xfg[((size_t)(o * 48 + i) << 14) + p] = f2bf(acc[nn][m][r]);
      }
    }
  }
}

// ---------------------------------------------------------------------------
// K4b: conv2 gather+GEMM, software-pipelined over TWO 8x32 y-tiles per block.
//  tile1's global loads issue BEFORE tile0's MFMA loop (held in regs),
//  hiding HBM/L3 latency under ~2000cy of MFMA. out stores nontemporal.
//  (R16 compile bug: q##S##0.x token-pasting hit the pp-number "0.x";
//   fixed by passing array names qA/qB explicitly.)
//  Register budget at (256,3) ~170: acc 48 + prefetch 36 + frags ~24 + addr
//  ~15 ~= 125 -> no spill expected (tell: WRITE_SIZE over ~149MB).
//  NaN invariant: pad [48,52) + 16-short tail zeroed; B1 spill -> next row's
//  i<16 x A-cols 48..63 = 0, or row 339 -> tail.
// ---------------------------------------------------------------------------
__global__ __launch_bounds__(256, 3) void conv2g_k(
    const unsigned short* __restrict__ xfg,
    const unsigned short* __restrict__ wbf64, float* __restrict__ out)
{
  __shared__ __align__(16) short XF[340 * XFP + 16];  // 10 rows x 34 cols

  int o  = blockIdx.z;
  int y0 = blockIdx.y * 16, x0 = blockIdx.x * 32;     // two tiles: y0, y0+8
  int tid = threadIdx.x;

  // phase 0: zero per-row pad shorts [48,52) and tail (NaN invariant)
  for (int p = tid; p < 340; p += 256)
    *(uint2*)(XF + p * XFP + 48) = make_uint2(0u, 0u);
  if (tid < 16) XF[340 * XFP + tid] = 0;

  // thread's two gather tasks (i, rr): tA = tid, tB = tid + 256 (if < 480)
  int iA = tid % 48,  rrA = tid / 48;
  int tB = tid + 256;
  bool hasB = (tB < 480);
  int iB = tB % 48, rrB = tB / 48;
  const size_t plA = ((size_t)(o * 48 + iA) << 14);
  const size_t plB = ((size_t)(o * 48 + iB) << 14);

  uint4 qA[4]; unsigned eA = 0; int yA = -1;
  uint4 qB[4]; unsigned eB = 0; int yB = -1;

#define GLOAD(Q, E, Y, pl, yy) { \
    Y = (yy); \
    if ((yy) >= 0 && (yy) < 128) { \
      const unsigned short* src_ = xfg + (pl) + ((yy) << 7); \
      Q[0] = *(const uint4*)(src_ + x0); \
      Q[1] = *(const uint4*)(src_ + x0 + 8); \
      Q[2] = *(const uint4*)(src_ + x0 + 16); \
      Q[3] = *(const uint4*)(src_ + x0 + 24); \
      unsigned e0_  = (x0 > 0)        ? (unsigned)src_[x0 - 1]  : 0u; \
      unsigned e33_ = (x0 + 32 < 128) ? (unsigned)src_[x0 + 32] : 0u; \
      E = e0_ | (e33_ << 16); \
    } }

#define GSTORE(Q, E, Y, ii, rr) { \
    short* dst_ = XF + (rr) * 34 * XFP + (ii); \
    if (Y >= 0 && Y < 128) { \
      unsigned qs_[16] = {Q[0].x, Q[0].y, Q[0].z, Q[0].w, \
                          Q[1].x, Q[1].y, Q[1].z, Q[1].w, \
                          Q[2].x, Q[2].y, Q[2].z, Q[2].w, \
                          Q[3].x, Q[3].y, Q[3].z, Q[3].w}; \
      dst_[0] = (short)(E & 0xffffu); \
      _Pragma("unroll") \
      for (int h = 0; h < 16; ++h) { \
        dst_[(2 * h + 1) * XFP] = (short)(qs_[h] & 0xffffu); \
        dst_[(2 * h + 2) * XFP] = (short)(qs_[h] >> 16); \
      } \
      dst_[33 * XFP] = (short)(E >> 16); \
    } else { \
      _Pragma("unroll") \
      for (int c = 0; c < 34; ++c) dst_[c * XFP] = 0; \
    } }

  int wv = tid >> 6, lane = tid & 63;
  int tx = lane & 15, gq = lane >> 4;
  const unsigned short* abase = wbf64 + (tx)*64;

#define MFMA_TILE(YBASE) { \
    f32x4 acc[2][2][3]; \
    _Pragma("unroll") \
    for (int h = 0; h < 2; ++h) \
      _Pragma("unroll") \
      for (int nn = 0; nn < 2; ++nn) \
        _Pragma("unroll") \
        for (int m = 0; m < 3; ++m) acc[h][nn][m] = (f32x4){0.f, 0.f, 0.f, 0.f}; \
    for (int k = 0; k < 9; ++k) { \
      bf16x8 Ac0[3], Ac1[3]; \
      _Pragma("unroll") \
      for (int m = 0; m < 3; ++m) { \
        const unsigned short* ap_ = abase + (k * 48 + m * 16) * 64; \
        Ac0[m] = *(const bf16x8*)(ap_ + gq * 8); \
        Ac1[m] = *(const bf16x8*)(ap_ + 32 + gq * 8); \
      } \
      int dy_ = k / 3, dx_ = k - dy_ * 3; \
      _Pragma("unroll") \
      for (int h = 0; h < 2; ++h) { \
        _Pragma("unroll") \
        for (int nn = 0; nn < 2; ++nn) { \
          int n_ = wv * 2 + nn; \
          const short* bp_ = XF + ((n_ + dy_) * 34 + h * 16 + tx + dx_) * XFP; \
          bf16x8 B0_ = *(const bf16x8*)(bp_ + gq * 8); \
          bf16x8 B1_ = *(const bf16x8*)(bp_ + 32 + gq * 8); \
          _Pragma("unroll") \
          for (int m = 0; m < 3; ++m) { \
            acc[h][nn][m] = __builtin_amdgcn_mfma_f32_16x16x32_bf16(Ac0[m], B0_, acc[h][nn][m], 0, 0, 0); \
            acc[h][nn][m] = __builtin_amdgcn_mfma_f32_16x16x32_bf16(Ac1[m], B1_, acc[h][nn][m], 0, 0, 0); \
          } \
        } \
      } \
    } \
    _Pragma("unroll") \
    for (int h = 0; h < 2; ++h) { \
      _Pragma("unroll") \
      for (int nn = 0; nn < 2; ++nn) { \
        int y_ = (YBASE) + wv * 2 + nn; \
        _Pragma("unroll") \
        for (int m = 0; m < 3; ++m) { \
          _Pragma("unroll") \
          for (int r = 0; r < 4; ++r) { \
            int oc_ = m * 16 + gq * 4 + r; \
            __builtin_nontemporal_store(acc[h][nn][m][r], \
              &out[((size_t)(o * COUT + oc_) << 14) + (y_ << 7) + x0 + h * 16 + tx]); \
          } \
        } \
      } \
    } }

  // ---- tile 0: gather -> LDS ----
  GLOAD(qA, eA, yA, plA, y0 - 1 + rrA)
  if (hasB) GLOAD(qB, eB, yB, plB, y0 - 1 + rrB)
  GSTORE(qA, eA, yA, iA, rrA)
  if (hasB) GSTORE(qB, eB, yB, iB, rrB)
  __syncthreads();

  // ---- prefetch tile 1's global data (hidden under tile 0 MFMA) ----
  GLOAD(qA, eA, yA, plA, y0 + 7 + rrA)
  if (hasB) GLOAD(qB, eB, yB, plB, y0 + 7 + rrB)

  // ---- tile 0: MFMA + nt-store ----
  MFMA_TILE(y0)

  __syncthreads();   // all waves done reading XF for tile 0

  // ---- tile 1: LDS write from prefetched regs ----
  GSTORE(qA, eA, yA, iA, rrA)
  if (hasB) GSTORE(qB, eB, yB, iB, rrB)
  __syncthreads();

  // ---- tile 1: MFMA + nt-store ----
  MFMA_TILE(y0 + 8)

#undef GLOAD
#undef GSTORE
#undef MFMA_TILE
}

// ---------------------------------------------------------------------------
// K4 (fallback, R12 verbatim): fused stencil + MFMA GEMM, (256,3) no-spill.
// ---------------------------------------------------------------------------
__global__ __launch_bounds__(256, 3) void conv2_k(
    const float* __restrict__ yf, const float* __restrict__ wts,
    const unsigned short* __restrict__ wbf64, float* __restrict__ out)
{
  __shared__ __align__(16) short XF[324 * XFP + 16];

  int o  = blockIdx.z;
  int y0 = blockIdx.y * 16, x0 = blockIdx.x * 16;
  int tid = threadIdx.x;

  for (int p = tid; p < 324; p += 256)
    *(uint2*)(XF + p * XFP + 48) = make_uint2(0u, 0u);
  if (tid < 16) XF[324 * XFP + tid] = 0;

  if (tid < 240) {
    int sA = tid, sB = tid + 240;
    int iA = sA / 10, rA = sA - iA * 10, spA = rA % 5, hA = rA / 5;
    int iB = sB / 10, rB = sB - iB * 10, spB = rB % 5, hB = rB / 5;
    const float* WpA = wts + (o * CIN + iA) * 9;
    const float* WpB = wts + (o * CIN + iB) * 9;
    float WA0 = WpA[0], WA1 = WpA[1], WA2 = WpA[2], WA3 = WpA[3], WA4 = WpA[4],
          WA5 = WpA[5], WA6 = WpA[6], WA7 = WpA[7], WA8 = WpA[8];
    float WB0 = WpB[0], WB1 = WpB[1], WB2 = WpB[2], WB3 = WpB[3], WB4 = WpB[4],
          WB5 = WpB[5], WB6 = WpB[6], WB7 = WpB[7], WB8 = WpB[8];
    const float* yfA = yf + iA * NPIX;
    const float* yfB = yf + iB * NPIX;
    int cbA = (x0 - 4 + 4 * spA) & 127;
    int cbB = (x0 - 4 + 4 * spB) & 127;
    int rbA = hA * 9, rbB = hB * 9;
    float RaA[8], RbA[8], RcA[8], RaB[8], RbB[8], RcB[8];

#define LOADA(dst, ry) { \
    const float* rp_ = yfA + (((ry) & 127) << 7); \
    float4 q0_ = *(const float4*)(rp_ + cbA); \
    float4 q1_ = *(const float4*)(rp_ + ((cbA + 4) & 127)); \
    dst[0]=q0_.x; dst[1]=q0_.y; dst[2]=q0_.z; dst[3]=q0_.w; \
    dst[4]=q1_.x; dst[5]=q1_.y; dst[6]=q1_.z; dst[7]=q1_.w; }
#define LOADB(dst, ry) { \
    const float* rp_ = yfB + (((ry) & 127) << 7); \
    float4 q0_ = *(const float4*)(rp_ + cbB); \
    float4 q1_ = *(const float4*)(rp_ + ((cbB + 4) & 127)); \
    dst[0]=q0_.x; dst[1]=q0_.y; dst[2]=q0_.z; dst[3]=q0_.w; \
    dst[4]=q1_.x; dst[5]=q1_.y; dst[6]=q1_.z; dst[7]=q1_.w; }
#define EMITA(rr, R2_, R1_, R0_) { \
    int y_ = y0 - 1 + (rr); \
    bool yok_ = (y_ >= 0) && (y_ < 128); \
    _Pragma("unroll") \
    for (int j = 0; j < 4; ++j) { \
      int cidx_ = 4 * spA + j; \
      if (cidx_ < 18) { \
        int xg_ = x0 - 1 + cidx_; \
        float v_ = 0.f; \
        if (yok_ && xg_ >= 0 && xg_ < 128) { \
          v_ = WA0 * R0_[j + 3] + WA1 * R0_[j + 2] + WA2 * R0_[j + 1] \
             + WA3 * R1_[j + 3] + WA4 * R1_[j + 2] + WA5 * R1_[j + 1] \
             + WA6 * R2_[j + 3] + WA7 * R2_[j + 2] + WA8 * R2_[j + 1]; \
        } \
        XF[((rr) * 18 + cidx_) * XFP + iA] = (short)f2bf(v_); \
      } } }
#define EMITB(rr, R2_, R1_, R0_) { \
    int y_ = y0 - 1 + (rr); \
    bool yok_ = (y_ >= 0) && (y_ < 128); \
    _Pragma("unroll") \
    for (int j = 0; j < 4; ++j) { \
      int cidx_ = 4 * spB + j; \
      if (cidx_ < 18) { \
        int xg_ = x0 - 1 + cidx_; \
        float v_ = 0.f; \
        if (yok_ && xg_ >= 0 && xg_ < 128) { \
          v_ = WB0 * R0_[j + 3] + WB1 * R0_[j + 2] + WB2 * R0_[j + 1] \
             + WB3 * R1_[j + 3] + WB4 * R1_[j + 2] + WB5 * R1_[j + 1] \
             + WB6 * R2_[j + 3] + WB7 * R2_[j + 2] + WB8 * R2_[j + 1]; \
        } \
        XF[((rr) * 18 + cidx_) * XFP + iB] = (short)f2bf(v_); \
      } } }

    LOADA(RaA, y0 - 3 + rbA)  LOADB(RaB, y0 - 3 + rbB)
    LOADA(RbA, y0 - 2 + rbA)  LOADB(RbB, y0 - 2 + rbB)
#pragma unroll
    for (int rr0 = 0; rr0 < 9; rr0 += 3) {
      LOADA(RcA, y0 - 1 + rbA + rr0)  LOADB(RcB, y0 - 1 + rbB + rr0)
      EMITA(rbA + rr0,     RaA, RbA, RcA)  EMITB(rbB + rr0,     RaB, RbB, RcB)
      LOADA(RaA, y0 + rbA + rr0)      LOADB(RaB, y0 + rbB + rr0)
      EMITA(rbA + rr0 + 1, RbA, RcA, RaA)  EMITB(rbB + rr0 + 1, RbB, RcB, RaB)
      LOADA(RbA, y0 + 1 + rbA + rr0)  LOADB(RbB, y0 + 1 + rbB + rr0)
      EMITA(rbA + rr0 + 2, RcA, RaA, RbA)  EMITB(rbB + rr0 + 2, RcB, RaB, RbB)
    }
#undef LOADA
#undef LOADB
#undef EMITA
#undef EMITB
  }
  __syncthreads();

  int wv = tid >> 6, lane = tid & 63;
  int tx = lane & 15, gq = lane >> 4;
  f32x4 acc[4][3];
#pragma unroll
  for (int nn = 0; nn < 4; ++nn)
#pragma unroll
    for (int m = 0; m < 3; ++m) acc[nn][m] = (f32x4){0.f, 0.f, 0.f, 0.f};

  const unsigned short* abase = wbf64 + (tx)*64;

  for (int k = 0; k < 9; ++k) {
    bf16x8 Ac0[3], Ac1[3];
#pragma unroll
    for (int m = 0; m < 3; ++m) {
      const unsigned short* ap = abase + (k * 48 + m * 16) * 64;
      Ac0[m] = *(const bf16x8*)(ap + gq * 8);
      Ac1[m] = *(const bf16x8*)(ap + 32 + gq * 8);
    }
    int dy = k / 3, dx = k - dy * 3;
#pragma unroll
    for (int nn = 0; nn < 4; ++nn) {
      int n = wv * 4 + nn;
      const short* bp = XF + ((n + dy) * 18 + tx + dx) * XFP;
      bf16x8 B0 = *(const bf16x8*)(bp + gq * 8);
      bf16x8 B1 = *(const bf16x8*)(bp + 32 + gq * 8);
#pragma unroll
      for (int m = 0; m < 3; ++m) {
        acc[nn][m] = __builtin_amdgcn_mfma_f32_16x16x32_bf16(Ac0[m], B0, acc[nn][m], 0, 0, 0);
        acc[nn][m] = __builtin_amdgcn_mfma_f32_16x16x32_bf16(Ac1[m], B1, acc[nn][m], 0, 0, 0);
      }
    }
  }

#pragma unroll
  for (int nn = 0; nn < 4; ++nn) {
    int y = y0 + wv * 4 + nn;
#pragma unroll
    for (int m = 0; m < 3; ++m) {
#pragma unroll
      for (int r = 0; r < 4; ++r) {
        int oc = m * 16 + gq * 4 + r;
        out[((size_t)(o * COUT + oc) << 14) + (y << 7) + x0 + tx] = acc[nn][m][r];
      }
    }
  }
}

// ---------------------------------------------------------------------------
extern "C" void kernel_launch(void* const* d_in, const int* in_sizes, int n_in,
                              void* d_out, int out_size, void* d_ws, size_t ws_size,
                              hipStream_t stream)
{
  const float* x      = (const float*)d_in[0];
  const float* freq   = (const float*)d_in[1];
  const float* theta  = (const float*)d_in[2];
  const float* sigma  = (const float*)d_in[3];
  const float* psi    = (const float*)d_in[4];
  const float* f0     = (const float*)d_in[5];
  const float* theta0 = (const float*)d_in[6];
  float* out = (float*)d_out;
  float* ws  = (float*)d_ws;

  float*  w      = ws;
  float*  ar     = ws + 20736;
  float*  ai     = ws + 20864;
  float2* Up     = (float2*)(ws + OFF_UP);
  float*  yf     = ws + OFF_YF;
  unsigned short* wbf64  = (unsigned short*)(ws + OFF_WBF64);
  unsigned int*   wsplit = (unsigned int*)(ws + OFF_WSPLIT);
  unsigned short* xfg    = (unsigned short*)(ws + OFF_XFG);

  int big = (ws_size >= WS_NEEDED) ? 1 : 0;

  gabor_k<<<dim3(126), dim3(256), 0, stream>>>(freq, theta, sigma, psi, f0, theta0,
                                               w, wbf64, wsplit, big);
  circ_k<<<dim3(1), dim3(128), 0, stream>>>(ar, ai);
  stage1_k<<<dim3(8, 48), dim3(256), 0, stream>>>(x, ar, ai, Up);
  stage2_k<<<dim3(8, 48), dim3(256), 0, stream>>>(Up, ar, ai, yf);
  if (big) {
    stageA_k<<<dim3(64, 48), dim3(256), 0, stream>>>(yf, (const unsigned short*)wsplit, xfg);
    conv2g_k<<<dim3(4, 8, 48), dim3(256), 0, stream>>>(xfg, wbf64, out);
  } else {
    conv2_k<<<dim3(8, 8, 48), dim3(256), 0, stream>>>(yf, w, wbf64, out);
  }
}

// Round 18
// 159.233 us; speedup vs baseline: 1.6770x; 1.6770x over previous
//
#include <hip/hip_runtime.h>

#define CIN 48
#define COUT 48
#define NPIX 16384  // 128*128
#define XFP 52      // XF pitch in shorts (104 B): bank conflicts 5.8M -> 0.88M (R11/R12)

typedef float f32x4 __attribute__((ext_vector_type(4)));
typedef short bf16x8 __attribute__((ext_vector_type(8)));

__device__ __forceinline__ unsigned short f2bf(float f) {
  unsigned u = __float_as_uint(f);
  unsigned r = (u + 0x7FFFu + ((u >> 16) & 1u)) >> 16;  // RNE
  return (unsigned short)r;
}

// ws layout (floats):
//   w[20736] | ar[128] | ai[128] | pad->21248 | Up[1572864] | yf[786432] | wbf64[13824]
#define OFF_UP     21248
#define OFF_YF     (OFF_UP + CIN * NPIX * 2)
#define OFF_WBF64  (OFF_YF + CIN * NPIX)

// ---------------------------------------------------------------------------
// K1: Gabor weights. f32 w[oc][i][9]; bf16 A-table wbf64[(k*48+oc)*64+i],
//     i pad [48,64) zeroed.
// ---------------------------------------------------------------------------
__global__ __launch_bounds__(256) void gabor_k(
    const float* __restrict__ freq, const float* __restrict__ theta,
    const float* __restrict__ sigma, const float* __restrict__ psi,
    const float* __restrict__ f0, const float* __restrict__ theta0,
    float* __restrict__ wout, unsigned short* __restrict__ wbf64)
{
  int idx = blockIdx.x * 256 + threadIdx.x;
  if (idx < 432 * 16) {
    wbf64[(idx >> 4) * 64 + 48 + (idx & 15)] = 0;
  }
  if (idx >= COUT * CIN * 9) return;
  int k = idx % 9;
  int oi = idx / 9;
  int oc = oi / CIN, ic = oi % CIN;
  int a = k / 3, b = k % 3;
  float Yv = (a == 0) ? -1.0f : ((a == 1) ? 0.5f : 2.0f);
  float Xv = (b == 0) ? -1.0f : ((b == 1) ? 0.5f : 2.0f);
  float th = theta[oi], sg = sigma[oi], fr = freq[oi], ps = psi[oi];
  float F0 = f0[oi], th0 = theta0[oi];
  float c = cosf(th), s = sinf(th);
  float rotx =  Xv * c + Yv * s;
  float roty = -Xv * s + Yv * c;
  float r = sqrtf(rotx * rotx + roty * roty + 0.001f);
  float denom = 2.0f * logf(sg / F0);
  float t1 = (logf(r) - logf(F0)) / denom;
  float g_rad = expf(-t1 * t1);
  float dth = th - th0;
  float g_ang = expf(-dth * dth / (2.0f * sg * sg));
  float g = g_rad * g_ang * cosf(fr * r + ps) / (6.283185307179586f * sg * sg);
  wout[idx] = g;
  wbf64[(k * 48 + oc) * 64 + ic] = f2bf(g);
}

// ---------------------------------------------------------------------------
// K2: circulant band-limit vector
// ---------------------------------------------------------------------------
__global__ void circ_k(float* __restrict__ ar, float* __restrict__ ai)
{
  int d = threadIdx.x;
  float sr = 0.f, si = 0.f;
  for (int u = 34; u < 94; ++u) {
    int m = (u * d) & 127;
    float ang = (float)m * 0.049087385212340526f;
    sr += cosf(ang);
    si += sinf(ang);
  }
  ar[d] = sr * (1.0f / 128.0f);
  ai[d] = si * (1.0f / 128.0f);
}

// ---------------------------------------------------------------------------
// K3a: row band-limit. grid (16, 48): 8 rows per block (more blocks ->
// 3 waves/SIMD for latency hiding; was 1.5 at grid 8).
// ---------------------------------------------------------------------------
__global__ __launch_bounds__(256) void stage1_k(
    const float* __restrict__ x, const float* __restrict__ arr,
    const float* __restrict__ aii, float2* __restrict__ Up)
{
  __shared__ float Xs[8 * 128];
  __shared__ float ars[128], ais[128];
  int yg = blockIdx.x, i = blockIdx.y;
  int t = threadIdx.x;
  const float* Xi = x + i * NPIX + yg * 8 * 128;
  for (int p = t; p < 1024; p += 256) Xs[p] = Xi[p];
  if (t < 128) { ars[t] = arr[t]; ais[t] = aii[t]; }
  __syncthreads();
  int j = t & 127;
  int ysl = t >> 7;                 // 0/1 -> 4 rows each
  float accr[4], acci[4];
#pragma unroll
  for (int yy = 0; yy < 4; ++yy) { accr[yy] = 0.f; acci[yy] = 0.f; }
  for (int xx = 0; xx < 128; ++xx) {
    float tr = ars[(j - xx) & 127];
    float ti = ais[(j - xx) & 127];
#pragma unroll
    for (int yy = 0; yy < 4; ++yy) {
      float xv = Xs[(ysl * 4 + yy) * 128 + xx];
      accr[yy] += xv * tr;
      acci[yy] += xv * ti;
    }
  }
  float2* UpI = Up + i * NPIX;
  int ybase = yg * 8 + ysl * 4;
#pragma unroll
  for (int yy = 0; yy < 4; ++yy)
    UpI[(ybase + yy) * 128 + j] = make_float2(accr[yy], acci[yy]);
}

// ---------------------------------------------------------------------------
// K3b: column band-limit. grid (16, 48): 8 cols per block. f32 output
// (R7: bf16 yf doubled output error and tripped the secondary check).
// ---------------------------------------------------------------------------
__global__ __launch_bounds__(256) void stage2_k(
    const float2* __restrict__ Up, const float* __restrict__ arr,
    const float* __restrict__ aii, float* __restrict__ yf)
{
  __shared__ float2 Us[128 * 8];
  __shared__ float ars[128], ais[128];
  int jg = blockIdx.x, i = blockIdx.y;
  int t = threadIdx.x;
  const float2* UpI = Up + i * NPIX;
  for (int p = t; p < 1024; p += 256) {
    int y = p >> 3, jj = p & 7;
    Us[p] = UpI[y * 128 + jg * 8 + jj];
  }
  if (t < 128) { ars[t] = arr[t]; ais[t] = aii[t]; }
  __syncthreads();
  int yp = t & 127;
  int xsl = t >> 7;                 // 0/1 -> 4 cols each
  float acc[4];
#pragma unroll
  for (int xx = 0; xx < 4; ++xx) acc[xx] = 0.f;
  for (int y = 0; y < 128; ++y) {
    float tr = ars[(yp - y) & 127];
    float ti = ais[(yp - y) & 127];
#pragma unroll
    for (int xx = 0; xx < 4; ++xx) {
      float2 u = Us[y * 8 + xsl * 4 + xx];
      acc[xx] += u.x * tr - u.y * ti;
    }
  }
  float* yfI = yf + i * NPIX;
  int xb = jg * 8 + xsl * 4;
#pragma unroll
  for (int xx = 0; xx < 4; ++xx)
    yfI[yp * 128 + xb + xx] = acc[xx];
}

// ---------------------------------------------------------------------------
// K4 (R12 base + interior fast-path + A-prefetch): fused stencil + MFMA GEMM.
//  (256,3) = proven no-spill point (unified VGPR/AGPR file; (256,4/5) spill).
//  LDS: XF[324 px][52 shorts] + 16-short zero tail = 33728 B.
//  NaN invariant: pad [48,52) + tail zeroed; B1 spill reads -> next row's
//  i<16 x A-cols 48..63 = 0, or row 323 -> zeroed tail.
//  Phase 1: 480 half-strip tasks, threads 0..239 run 2 interleaved; tiles
//  with x0,y0 in [16,96] are INTERIOR -> wave-uniform branch skips all
//  bounds checks (36/64 of blocks; value-identical math).
//  Phase 2: 16x16x32_bf16 only; A zero-padded i>=48; A double-buffered
//  (R6-proven at 84 VGPR, no spill).
// ---------------------------------------------------------------------------
__global__ __launch_bounds__(256, 3) void conv2_k(
    const float* __restrict__ yf, const float* __restrict__ wts,
    const unsigned short* __restrict__ wbf64, float* __restrict__ out)
{
  __shared__ __align__(16) short XF[324 * XFP + 16];

  int o  = blockIdx.z;
  int y0 = blockIdx.y * 16, x0 = blockIdx.x * 16;
  int tid = threadIdx.x;

  // phase 0: zero per-row pad shorts [48,52) and tail (NaN invariant)
  for (int p = tid; p < 324; p += 256)
    *(uint2*)(XF + p * XFP + 48) = make_uint2(0u, 0u);
  if (tid < 16) XF[324 * XFP + tid] = 0;

  // phase 1: xf(y,x) = sum_{dy,dx in 0..2} w[dy,dx] * yf((y-dy)&127,(x-dx)&127)
  bool inter = (y0 >= 16) && (y0 <= 96) && (x0 >= 16) && (x0 <= 96);
  if (tid < 240) {
    int sA = tid, sB = tid + 240;
    int iA = sA / 10, rA = sA - iA * 10, spA = rA % 5, hA = rA / 5;
    int iB = sB / 10, rB = sB - iB * 10, spB = rB % 5, hB = rB / 5;
    const float* WpA = wts + (o * CIN + iA) * 9;
    const float* WpB = wts + (o * CIN + iB) * 9;
    float WA0 = WpA[0], WA1 = WpA[1], WA2 = WpA[2], WA3 = WpA[3], WA4 = WpA[4],
          WA5 = WpA[5], WA6 = WpA[6], WA7 = WpA[7], WA8 = WpA[8];
    float WB0 = WpB[0], WB1 = WpB[1], WB2 = WpB[2], WB3 = WpB[3], WB4 = WpB[4],
          WB5 = WpB[5], WB6 = WpB[6], WB7 = WpB[7], WB8 = WpB[8];
    const float* yfA = yf + iA * NPIX;
    const float* yfB = yf + iB * NPIX;
    int cbA = (x0 - 4 + 4 * spA) & 127;   // mult of 4 -> float4 aligned, wrap-safe
    int cbB = (x0 - 4 + 4 * spB) & 127;
    int rbA = hA * 9, rbB = hB * 9;
    float RaA[8], RbA[8], RcA[8], RaB[8], RbB[8], RcB[8];

#define LOADA(dst, ry) { \
    const float* rp_ = yfA + (((ry) & 127) << 7); \
    float4 q0_ = *(const float4*)(rp_ + cbA); \
    float4 q1_ = *(const float4*)(rp_ + ((cbA + 4) & 127)); \
    dst[0]=q0_.x; dst[1]=q0_.y; dst[2]=q0_.z; dst[3]=q0_.w; \
    dst[4]=q1_.x; dst[5]=q1_.y; dst[6]=q1_.z; dst[7]=q1_.w; }
#define LOADB(dst, ry) { \
    const float* rp_ = yfB + (((ry) & 127) << 7); \
    float4 q0_ = *(const float4*)(rp_ + cbB); \
    float4 q1_ = *(const float4*)(rp_ + ((cbB + 4) & 127)); \
    dst[0]=q0_.x; dst[1]=q0_.y; dst[2]=q0_.z; dst[3]=q0_.w; \
    dst[4]=q1_.x; dst[5]=q1_.y; dst[6]=q1_.z; dst[7]=q1_.w; }

#define EMITA(rr, R2_, R1_, R0_, CHK) { \
    int y_ = y0 - 1 + (rr); \
    _Pragma("unroll") \
    for (int j = 0; j < 4; ++j) { \
      int cidx_ = 4 * spA + j; \
      if (cidx_ < 18) { \
        float v_ = WA0 * R0_[j + 3] + WA1 * R0_[j + 2] + WA2 * R0_[j + 1] \
                 + WA3 * R1_[j + 3] + WA4 * R1_[j + 2] + WA5 * R1_[j + 1] \
                 + WA6 * R2_[j + 3] + WA7 * R2_[j + 2] + WA8 * R2_[j + 1]; \
        if (CHK) { \
          int xg_ = x0 - 1 + cidx_; \
          if (!((y_ >= 0) && (y_ < 128) && (xg_ >= 0) && (xg_ < 128))) v_ = 0.f; \
        } \
        XF[((rr) * 18 + cidx_) * XFP + iA] = (short)f2bf(v_); \
      } } }
#define EMITB(rr, R2_, R1_, R0_, CHK) { \
    int y_ = y0 - 1 + (rr); \
    _Pragma("unroll") \
    for (int j = 0; j < 4; ++j) { \
      int cidx_ = 4 * spB + j; \
      if (cidx_ < 18) { \
        float v_ = WB0 * R0_[j + 3] + WB1 * R0_[j + 2] + WB2 * R0_[j + 1] \
                 + WB3 * R1_[j + 3] + WB4 * R1_[j + 2] + WB5 * R1_[j + 1] \
                 + WB6 * R2_[j + 3] + WB7 * R2_[j + 2] + WB8 * R2_[j + 1]; \
        if (CHK) { \
          int xg_ = x0 - 1 + cidx_; \
          if (!((y_ >= 0) && (y_ < 128) && (xg_ >= 0) && (xg_ < 128))) v_ = 0.f; \
        } \
        XF[((rr) * 18 + cidx_) * XFP + iB] = (short)f2bf(v_); \
      } } }

#define PH1LOOP(CHK) { \
    LOADA(RaA, y0 - 3 + rbA)  LOADB(RaB, y0 - 3 + rbB) \
    LOADA(RbA, y0 - 2 + rbA)  LOADB(RbB, y0 - 2 + rbB) \
    _Pragma("unroll") \
    for (int rr0 = 0; rr0 < 9; rr0 += 3) { \
      LOADA(RcA, y0 - 1 + rbA + rr0)  LOADB(RcB, y0 - 1 + rbB + rr0) \
      EMITA(rbA + rr0,     RaA, RbA, RcA, CHK)  EMITB(rbB + rr0,     RaB, RbB, RcB, CHK) \
      LOADA(RaA, y0 + rbA + rr0)      LOADB(RaB, y0 + rbB + rr0) \
      EMITA(rbA + rr0 + 1, RbA, RcA, RaA, CHK)  EMITB(rbB + rr0 + 1, RbB, RcB, RaB, CHK) \
      LOADA(RbA, y0 + 1 + rbA + rr0)  LOADB(RbB, y0 + 1 + rbB + rr0) \
      EMITA(rbA + rr0 + 2, RcA, RaA, RbA, CHK)  EMITB(rbB + rr0 + 2, RcB, RaB, RbB, CHK) \
    } }

    if (inter) PH1LOOP(0) else PH1LOOP(1)

#undef LOADA
#undef LOADB
#undef EMITA
#undef EMITB
#undef PH1LOOP
  }
  __syncthreads();

  // phase 2: MFMA GEMM, 16x16x32_bf16 only, A double-buffered
  int wv = tid >> 6, lane = tid & 63;
  int tx = lane & 15, gq = lane >> 4;
  f32x4 acc[4][3];
#pragma unroll
  for (int nn = 0; nn < 4; ++nn)
#pragma unroll
    for (int m = 0; m < 3; ++m) acc[nn][m] = (f32x4){0.f, 0.f, 0.f, 0.f};

  const unsigned short* abase = wbf64 + (tx)*64;
  bf16x8 Ac0[3], Ac1[3], An0[3], An1[3];
#pragma unroll
  for (int m = 0; m < 3; ++m) {
    const unsigned short* ap = abase + (m * 16) * 64;
    Ac0[m] = *(const bf16x8*)(ap + gq * 8);
    Ac1[m] = *(const bf16x8*)(ap + 32 + gq * 8);
  }

  for (int k = 0; k < 9; ++k) {
    if (k < 8) {
#pragma unroll
      for (int m = 0; m < 3; ++m) {
        const unsigned short* ap = abase + ((k + 1) * 48 + m * 16) * 64;
        An0[m] = *(const bf16x8*)(ap + gq * 8);
        An1[m] = *(const bf16x8*)(ap + 32 + gq * 8);
      }
    }
    int dy = k / 3, dx = k - dy * 3;
#pragma unroll
    for (int nn = 0; nn < 4; ++nn) {
      int n = wv * 4 + nn;
      const short* bp = XF + ((n + dy) * 18 + tx + dx) * XFP;
      bf16x8 B0 = *(const bf16x8*)(bp + gq * 8);
      bf16x8 B1 = *(const bf16x8*)(bp + 32 + gq * 8);  // pad/next-row, A=0 there
#pragma unroll
      for (int m = 0; m < 3; ++m) {
        acc[nn][m] = __builtin_amdgcn_mfma_f32_16x16x32_bf16(Ac0[m], B0, acc[nn][m], 0, 0, 0);
        acc[nn][m] = __builtin_amdgcn_mfma_f32_16x16x32_bf16(Ac1[m], B1, acc[nn][m], 0, 0, 0);
      }
    }
#pragma unroll
    for (int m = 0; m < 3; ++m) { Ac0[m] = An0[m]; Ac1[m] = An1[m]; }
  }

  // epilogue: C frag col=lane&15 (pixel x), row=gq*4+r (oc)
#pragma unroll
  for (int nn = 0; nn < 4; ++nn) {
    int y = y0 + wv * 4 + nn;
#pragma unroll
    for (int m = 0; m < 3; ++m) {
#pragma unroll
      for (int r = 0; r < 4; ++r) {
        int oc = m * 16 + gq * 4 + r;
        out[((size_t)(o * COUT + oc) << 14) + (y << 7) + x0 + tx] = acc[nn][m][r];
      }
    }
  }
}

// ---------------------------------------------------------------------------
extern "C" void kernel_launch(void* const* d_in, const int* in_sizes, int n_in,
                              void* d_out, int out_size, void* d_ws, size_t ws_size,
                              hipStream_t stream)
{
  const float* x      = (const float*)d_in[0];
  const float* freq   = (const float*)d_in[1];
  const float* theta  = (const float*)d_in[2];
  const float* sigma  = (const float*)d_in[3];
  const float* psi    = (const float*)d_in[4];
  const float* f0     = (const float*)d_in[5];
  const float* theta0 = (const float*)d_in[6];
  float* out = (float*)d_out;
  float* ws  = (float*)d_ws;

  float*  w     = ws;
  float*  ar    = ws + 20736;
  float*  ai    = ws + 20864;
  float2* Up    = (float2*)(ws + OFF_UP);
  float*  yf    = ws + OFF_YF;
  unsigned short* wbf64 = (unsigned short*)(ws + OFF_WBF64);

  gabor_k<<<dim3(81), dim3(256), 0, stream>>>(freq, theta, sigma, psi, f0, theta0, w, wbf64);
  circ_k<<<dim3(1), dim3(128), 0, stream>>>(ar, ai);
  stage1_k<<<dim3(16, 48), dim3(256), 0, stream>>>(x, ar, ai, Up);
  stage2_k<<<dim3(16, 48), dim3(256), 0, stream>>>(Up, ar, ai, yf);
  conv2_k<<<dim3(8, 8, 48), dim3(256), 0, stream>>>(yf, w, wbf64, out);
}